// Round 2
// baseline (362.799 us; speedup 1.0000x reference)
//
#include <hip/hip_runtime.h>
#include <hip/hip_bf16.h>
#include <math.h>

#define BB 4096
#define TT 48
#define FF 64
#define HH 128
#define ROWS 16
#define NT 512
#define NBLK (BB / ROWS)   // 256

typedef __attribute__((ext_vector_type(8))) short short8;
typedef __attribute__((ext_vector_type(4))) float f32x4;

#define MFMA(a, b, c) __builtin_amdgcn_mfma_f32_16x16x32_bf16((a), (b), (c), 0, 0, 0)

__device__ __forceinline__ float sigm(float x) { return 1.f / (1.f + __expf(-x)); }
__device__ __forceinline__ float tanh_f(float x) { return 2.f / (1.f + __expf(-2.f * x)) - 1.f; }

// ---- prep: pre-format ALL weights as bf16 MFMA B-fragments ----
// frag[...][lane][jj]: n = nt*16 + (lane&15), k = ks*32 + (lane>>4)*8 + jj
// Regions (element offsets):
//   [0,131072)        Wcat [512][256]  (W_ih | W_hh), 32 nt x 8 ks
//   [131072,139264)   Wdh  [128][64],   8 nt x 2 ks
//   [139264,147456)   Wh   [64][128],   4 nt x 4 ks
//   [147456,151552)   Wf   [64][64] diag-zeroed, 4 nt x 2 ks
//   [151552,159744)   Wc   [64][128],   4 nt x 4 ks
__global__ __launch_bounds__(256) void prep_kernel(
    const float* __restrict__ W_ih, const float* __restrict__ W_hh,
    const float* __restrict__ Wdh,  const float* __restrict__ Wh,
    const float* __restrict__ Wf,   const float* __restrict__ Wc,
    __hip_bfloat16* __restrict__ frags) {
    const int idx = blockIdx.x * 256 + threadIdx.x;  // < 159744
    float v;
    if (idx < 131072) {
        const int jj = idx & 7;
        const int lane = (idx >> 3) & 63;
        const int ks = (idx >> 9) & 7;
        const int tile = idx >> 12;
        const int n = tile * 16 + (lane & 15);
        const int k = ks * 32 + ((lane >> 4) << 3) + jj;
        v = (k < 128) ? W_ih[n * 128 + k] : W_hh[n * 128 + (k - 128)];
    } else {
        const int u = idx - 131072;
        const int jj = u & 7;
        const int lane = (u >> 3) & 63;
        const int lq = lane & 15, q8 = (lane >> 4) << 3;
        if (u < 8192) {                       // Wdh
            const int ks = (u >> 9) & 1, nt = u >> 10;
            const int n = nt * 16 + lq, k = ks * 32 + q8 + jj;
            v = Wdh[n * 64 + k];
        } else if (u < 16384) {               // Wh
            const int uu = u - 8192;
            const int ks = (uu >> 9) & 3, nt = uu >> 11;
            const int n = nt * 16 + lq, k = ks * 32 + q8 + jj;
            v = Wh[n * 128 + k];
        } else if (u < 20480) {               // Wf (diag zero)
            const int uu = u - 16384;
            const int ks = (uu >> 9) & 1, nt = uu >> 10;
            const int n = nt * 16 + lq, k = ks * 32 + q8 + jj;
            v = (k == n) ? 0.f : Wf[n * 64 + k];
        } else {                              // Wc
            const int uu = u - 20480;
            const int ks = (uu >> 9) & 3, nt = uu >> 11;
            const int n = nt * 16 + lq, k = ks * 32 + q8 + jj;
            v = Wc[n * 128 + k];
        }
    }
    frags[idx] = __float2bfloat16(v);
}

// ---- denom stage 1: partials[t*32+s] = sum over b-slice s (128 rows) of masks[b][t][:]
__global__ __launch_bounds__(256) void denom1_kernel(const float* __restrict__ masks,
                                                     float* __restrict__ partials) {
    const int t = blockIdx.x >> 5;
    const int s = blockIdx.x & 31;
    const int tid = threadIdx.x;
    float acc = 0.f;
    #pragma unroll
    for (int k = 0; k < 8; ++k) {
        const int i = k * 256 + tid;            // 0..2047 float4s
        const int b = s * 128 + (i >> 4);
        const int f = (i & 15) << 2;
        const float4 v = *(const float4*)&masks[((size_t)b * TT + t) * FF + f];
        acc += v.x + v.y + v.z + v.w;
    }
    #pragma unroll
    for (int off = 32; off; off >>= 1) acc += __shfl_down(acc, off, 64);
    __shared__ float red[4];
    if ((tid & 63) == 0) red[tid >> 6] = acc;
    __syncthreads();
    if (tid == 0) partials[blockIdx.x] = red[0] + red[1] + red[2] + red[3];
}

__global__ __launch_bounds__(64) void denom2_kernel(const float* __restrict__ partials,
                                                    float* __restrict__ inv_denom) {
    const int t = threadIdx.x;
    if (t < TT) {
        float s = 0.f;
        #pragma unroll
        for (int i = 0; i < 32; ++i) s += partials[t * 32 + i];
        inv_denom[t] = 1.f / (s + 1e-5f);
    }
}

// ---- Main persistent kernel ----
// Phases per step (4 barriers):
//  A: gamma_h (1 tile/wave, h decays IN REGISTERS -> hbufB) + alpha(w0-3, regs) + prefetch
//  B: gates h-part (ks4-7, all waves, reg acc) ; x_h + x_c (w0-3)
//  C: gates m-part (ks2-3) ; z_h + combine + loss + out_imp (w0-3)
//  D: gates cc-part (ks0-1) + LSTM epilogue (h_reg/c_reg) + stage t+1
__global__ __launch_bounds__(NT, 2) void rits_kernel(
    const float* __restrict__ values, const float* __restrict__ masks,
    const float* __restrict__ deltas,
    const float* __restrict__ Wdx, const float* __restrict__ bdx,
    const float* __restrict__ bdh, const float* __restrict__ bh,
    const float* __restrict__ bf,  const float* __restrict__ bc,
    const float* __restrict__ b_ih, const float* __restrict__ b_hh,
    const float* __restrict__ Wo,  const float* __restrict__ bo,
    const __hip_bfloat16* __restrict__ frags,
    const float* __restrict__ inv_denom,
    float* __restrict__ ws_lossblk,
    float* __restrict__ out_imp, float* __restrict__ out_pred)
{
    __shared__ __hip_bfloat16 dbuf[ROWS][72];    // deltas (staged in D for t+1)
    __shared__ __hip_bfloat16 gxbuf[ROWS][72];   // gamma_x
    __shared__ __hip_bfloat16 mbuf[ROWS][72];    // m (stored ONCE)
    __shared__ __hip_bfloat16 xcbuf[ROWS][72];   // x_c (B -> C)
    __shared__ __hip_bfloat16 ccbuf[ROWS][72];   // c_c (C -> D)
    __shared__ __hip_bfloat16 hbufB[ROWS][136];  // decayed h (A -> B)
    __shared__ float x_lds[ROWS][65];            // x fp32 (D -> B)
    __shared__ float m_lds[ROWS][65];            // m fp32 (D -> B)
    __shared__ float redl[8];

    const int tid = threadIdx.x;
    const int bid = blockIdx.x;
    const int b0 = bid * ROWS;
    const int lane = tid & 63;
    const int wv = tid >> 6;        // wave 0..7
    const int quad = lane >> 4;
    const int lq = lane & 15;
    const int wv3 = wv & 3;

    const float wdx_l = Wdx[lane * (FF + 1)];
    const float bdx_l = bdx[lane];

    const int j_ln = wv * 16 + lq;
    const float bdh_w = bdh[j_ln];                 // gamma tile wv <-> col j_ln
    const float bI = b_ih[j_ln]       + b_hh[j_ln];
    const float bF = b_ih[128 + j_ln] + b_hh[128 + j_ln];
    const float bG = b_ih[256 + j_ln] + b_hh[256 + j_ln];
    const float bO = b_ih[384 + j_ln] + b_hh[384 + j_ln];

    const int f46 = wv3 * 16 + lq;
    const float bh_f = bh[f46];
    const float bf_f = bf[f46];
    const float bc_f = bc[f46];

    const short8* f8 = (const short8*)frags;
    // short8-unit offsets: CAT 0, DH 16384, H 17408, F 18432, C 18944

    // loop-invariant small B-fragments cached in registers
    short8 Bgam[2], Bal[4], Bxh[4], Bzh[2];
    #pragma unroll
    for (int ks = 0; ks < 2; ++ks) Bgam[ks] = f8[16384 + ((wv * 2 + ks) << 6) + lane];
    #pragma unroll
    for (int ks = 0; ks < 4; ++ks) Bal[ks] = f8[18944 + ((wv3 * 4 + ks) << 6) + lane];
    #pragma unroll
    for (int ks = 0; ks < 4; ++ks) Bxh[ks] = f8[17408 + ((wv3 * 4 + ks) << 6) + lane];
    #pragma unroll
    for (int ks = 0; ks < 2; ++ks) Bzh[ks] = f8[18432 + ((wv3 * 2 + ks) << 6) + lane];

    const int gbase = (wv << 9) + lane;  // gates B-frag base: + g*4096 + ks*64

    float c_reg[4], h_reg[4];
    #pragma unroll
    for (int r = 0; r < 4; ++r) { c_reg[r] = 0.f; h_reg[r] = 0.f; }
    float loss_acc = 0.f;

    const int base0 = ((b0 + wv) * TT) * FF + lane;
    const int base1 = ((b0 + wv + 8) * TT) * FF + lane;
    const int imp0  = ((b0 + quad * 4) * TT) * FF + f46;

    // ---- prologue: load + stage t=0 ----
    float xn0 = values[base0], mn0 = masks[base0], dn0 = deltas[base0];
    float xn1 = values[base1], mn1 = masks[base1], dn1 = deltas[base1];
    {
        const int r0 = wv, r1 = wv + 8;
        x_lds[r0][lane] = xn0; m_lds[r0][lane] = mn0;
        dbuf[r0][lane]  = __float2bfloat16(dn0);
        gxbuf[r0][lane] = __float2bfloat16(__expf(-fmaxf(fmaf(dn0, wdx_l, bdx_l), 0.f)));
        mbuf[r0][lane]  = __float2bfloat16(mn0);
        x_lds[r1][lane] = xn1; m_lds[r1][lane] = mn1;
        dbuf[r1][lane]  = __float2bfloat16(dn1);
        gxbuf[r1][lane] = __float2bfloat16(__expf(-fmaxf(fmaf(dn1, wdx_l, bdx_l), 0.f)));
        mbuf[r1][lane]  = __float2bfloat16(mn1);
    }
    __syncthreads();

    for (int t = 0; t < TT; ++t) {
        const float invd = inv_denom[t];

        // ---- Phase A: prefetch t+1 ; gamma_h (all waves, 1 tile) ; alpha (w0-3) ----
        {
            const int tn = (t < TT - 1) ? t + 1 : t;
            const int o0 = base0 + tn * FF, o1 = base1 + tn * FF;
            xn0 = values[o0]; mn0 = masks[o0]; dn0 = deltas[o0];
            xn1 = values[o1]; mn1 = masks[o1]; dn1 = deltas[o1];
        }
        float al_r[4];
        {
            f32x4 ga = {0.f, 0.f, 0.f, 0.f};
            #pragma unroll
            for (int ks = 0; ks < 2; ++ks) {
                const short8 a = *(const short8*)&dbuf[lq][ks * 32 + quad * 8];
                ga = MFMA(a, Bgam[ks], ga);
            }
            if (wv < 4) {
                f32x4 aa = {0.f, 0.f, 0.f, 0.f};
                #pragma unroll
                for (int ks = 0; ks < 2; ++ks) {
                    const short8 a = *(const short8*)&gxbuf[lq][ks * 32 + quad * 8];
                    aa = MFMA(a, Bal[ks], aa);
                }
                #pragma unroll
                for (int ks = 2; ks < 4; ++ks) {
                    const short8 a = *(const short8*)&mbuf[lq][(ks - 2) * 32 + quad * 8];
                    aa = MFMA(a, Bal[ks], aa);
                }
                #pragma unroll
                for (int r = 0; r < 4; ++r) al_r[r] = aa[r] + bc_f;
            }
            #pragma unroll
            for (int r = 0; r < 4; ++r) {
                const float gh = __expf(-fmaxf(ga[r] + bdh_w, 0.f));
                hbufB[quad * 4 + r][j_ln] = __float2bfloat16(h_reg[r] * gh);
            }
        }
        __syncthreads();

        // ---- Phase B: gates h-part (all) ; x_h + x_c (w0-3) ----
        f32x4 gacc0 = {0.f,0.f,0.f,0.f}, gacc1 = {0.f,0.f,0.f,0.f};
        f32x4 gacc2 = {0.f,0.f,0.f,0.f}, gacc3 = {0.f,0.f,0.f,0.f};
        #pragma unroll
        for (int ks = 4; ks < 8; ++ks) {
            const short8 a = *(const short8*)&hbufB[lq][(ks - 4) * 32 + quad * 8];
            gacc0 = MFMA(a, f8[gbase + 0     + (ks << 6)], gacc0);
            gacc1 = MFMA(a, f8[gbase + 4096  + (ks << 6)], gacc1);
            gacc2 = MFMA(a, f8[gbase + 8192  + (ks << 6)], gacc2);
            gacc3 = MFMA(a, f8[gbase + 12288 + (ks << 6)], gacc3);
        }
        float xv_r[4], mv_r[4], xh_r[4];
        float stepsum = 0.f;
        if (wv < 4) {
            f32x4 acc = {0.f, 0.f, 0.f, 0.f};
            #pragma unroll
            for (int ks = 0; ks < 4; ++ks) {
                const short8 a = *(const short8*)&hbufB[lq][ks * 32 + quad * 8];
                acc = MFMA(a, Bxh[ks], acc);
            }
            #pragma unroll
            for (int r = 0; r < 4; ++r) {
                const int row = quad * 4 + r;
                const float xh = acc[r] + bh_f;
                xh_r[r] = xh;
                const float xv = x_lds[row][f46], mv = m_lds[row][f46];
                xv_r[r] = xv; mv_r[r] = mv;
                stepsum += mv * fabsf(xv - xh);
                xcbuf[row][f46] = __float2bfloat16(fmaf(mv, xv, (1.f - mv) * xh));
            }
        }
        __syncthreads();

        // ---- Phase C: gates m-part (all) ; z_h + combine (w0-3) ----
        #pragma unroll
        for (int ks = 2; ks < 4; ++ks) {
            const short8 a = *(const short8*)&mbuf[lq][(ks - 2) * 32 + quad * 8];
            gacc0 = MFMA(a, f8[gbase + 0     + (ks << 6)], gacc0);
            gacc1 = MFMA(a, f8[gbase + 4096  + (ks << 6)], gacc1);
            gacc2 = MFMA(a, f8[gbase + 8192  + (ks << 6)], gacc2);
            gacc3 = MFMA(a, f8[gbase + 12288 + (ks << 6)], gacc3);
        }
        if (wv < 4) {
            f32x4 acc5 = {0.f, 0.f, 0.f, 0.f};
            #pragma unroll
            for (int ks = 0; ks < 2; ++ks) {
                const short8 a = *(const short8*)&xcbuf[lq][ks * 32 + quad * 8];
                acc5 = MFMA(a, Bzh[ks], acc5);
            }
            #pragma unroll
            for (int r = 0; r < 4; ++r) {
                const int row = quad * 4 + r;
                const float zh = acc5[r] + bf_f;
                stepsum += mv_r[r] * fabsf(xv_r[r] - zh);
                const float alpha = al_r[r];
                const float ch = fmaf(alpha, zh, (1.f - alpha) * xh_r[r]);
                stepsum += mv_r[r] * fabsf(xv_r[r] - ch);
                const float cc = fmaf(mv_r[r], xv_r[r], (1.f - mv_r[r]) * ch);
                ccbuf[row][f46] = __float2bfloat16(cc);
                out_imp[imp0 + r * (TT * FF) + t * FF] = cc;
            }
        }
        loss_acc = fmaf(stepsum, invd, loss_acc);
        __syncthreads();

        // ---- Phase D: gates cc-part ; LSTM epilogue (regs) ; stage t+1 ----
        #pragma unroll
        for (int ks = 0; ks < 2; ++ks) {
            const short8 a = *(const short8*)&ccbuf[lq][ks * 32 + quad * 8];
            gacc0 = MFMA(a, f8[gbase + 0     + (ks << 6)], gacc0);
            gacc1 = MFMA(a, f8[gbase + 4096  + (ks << 6)], gacc1);
            gacc2 = MFMA(a, f8[gbase + 8192  + (ks << 6)], gacc2);
            gacc3 = MFMA(a, f8[gbase + 12288 + (ks << 6)], gacc3);
        }
        // stage t+1 (independent of gate results -> overlaps MFMA latency)
        {
            const int r0 = wv, r1 = wv + 8;
            x_lds[r0][lane] = xn0; m_lds[r0][lane] = mn0;
            dbuf[r0][lane]  = __float2bfloat16(dn0);
            gxbuf[r0][lane] = __float2bfloat16(__expf(-fmaxf(fmaf(dn0, wdx_l, bdx_l), 0.f)));
            mbuf[r0][lane]  = __float2bfloat16(mn0);
            x_lds[r1][lane] = xn1; m_lds[r1][lane] = mn1;
            dbuf[r1][lane]  = __float2bfloat16(dn1);
            gxbuf[r1][lane] = __float2bfloat16(__expf(-fmaxf(fmaf(dn1, wdx_l, bdx_l), 0.f)));
            mbuf[r1][lane]  = __float2bfloat16(mn1);
        }
        #pragma unroll
        for (int r = 0; r < 4; ++r) {
            const float ig = sigm(gacc0[r] + bI);
            const float fg = sigm(gacc1[r] + bF);
            const float gg = tanh_f(gacc2[r] + bG);
            const float og = sigm(gacc3[r] + bO);
            c_reg[r] = fmaf(fg, c_reg[r], ig * gg);
            h_reg[r] = og * tanh_f(c_reg[r]);
        }
        __syncthreads();
    }

    // ---- predictions: write final h (regs) to LDS, then reduce h @ Wo.T + bo ----
    #pragma unroll
    for (int r = 0; r < 4; ++r)
        hbufB[quad * 4 + r][j_ln] = __float2bfloat16(h_reg[r]);
    __syncthreads();
    {
        const int r = tid >> 5, l = tid & 31;
        float s = 0.f;
        #pragma unroll
        for (int k = l; k < HH; k += 32) s += __bfloat162float(hbufB[r][k]) * Wo[k];
        #pragma unroll
        for (int off = 16; off; off >>= 1) s += __shfl_down(s, off, 32);
        if (l == 0) out_pred[b0 + r] = s + bo[0];
    }
    // ---- block loss partial ----
    #pragma unroll
    for (int off = 32; off; off >>= 1) loss_acc += __shfl_down(loss_acc, off, 64);
    if (lane == 0) redl[wv] = loss_acc;
    __syncthreads();
    if (tid == 0) {
        float s = 0.f;
        #pragma unroll
        for (int w = 0; w < 8; ++w) s += redl[w];
        ws_lossblk[bid] = s;
    }
}

// ---- final: loss = sum of 256 block partials ----
__global__ __launch_bounds__(256) void final_kernel(const float* __restrict__ ws_lossblk,
                                                    float* __restrict__ out_loss) {
    const int tid = threadIdx.x;
    float s = ws_lossblk[tid];
    #pragma unroll
    for (int off = 32; off; off >>= 1) s += __shfl_down(s, off, 64);
    __shared__ float red[4];
    if ((tid & 63) == 0) red[tid >> 6] = s;
    __syncthreads();
    if (tid == 0) out_loss[0] = red[0] + red[1] + red[2] + red[3];
}

extern "C" void kernel_launch(void* const* d_in, const int* in_sizes, int n_in,
                              void* d_out, int out_size, void* d_ws, size_t ws_size,
                              hipStream_t stream) {
    const float* values = (const float*)d_in[0];
    const float* masks  = (const float*)d_in[1];
    const float* deltas = (const float*)d_in[2];
    const float* Wdh  = (const float*)d_in[3];
    const float* bdh  = (const float*)d_in[4];
    const float* Wdx  = (const float*)d_in[5];
    const float* bdx  = (const float*)d_in[6];
    const float* Wh   = (const float*)d_in[7];
    const float* bh   = (const float*)d_in[8];
    const float* Wf   = (const float*)d_in[9];
    const float* bf   = (const float*)d_in[10];
    const float* Wc   = (const float*)d_in[11];
    const float* bc   = (const float*)d_in[12];
    const float* W_ih = (const float*)d_in[13];
    const float* W_hh = (const float*)d_in[14];
    const float* b_ih = (const float*)d_in[15];
    const float* b_hh = (const float*)d_in[16];
    const float* Wo   = (const float*)d_in[17];
    const float* bo   = (const float*)d_in[18];

    __hip_bfloat16* frags = (__hip_bfloat16*)d_ws;                 // 159744 bf16 = 319488 B
    float* inv_denom  = (float*)((char*)d_ws + 320 * 1024);        // [48] (pad to 64)
    float* partials   = inv_denom + 64;                            // [48*32]
    float* ws_lossblk = partials + 2048;                           // [256]

    float* out_loss = (float*)d_out;
    float* out_imp  = out_loss + 1;
    float* out_pred = out_imp + (size_t)BB * TT * FF;

    prep_kernel<<<624, 256, 0, stream>>>(W_ih, W_hh, Wdh, Wh, Wf, Wc, frags);
    denom1_kernel<<<TT * 32, 256, 0, stream>>>(masks, partials);
    denom2_kernel<<<1, 64, 0, stream>>>(partials, inv_denom);
    rits_kernel<<<NBLK, NT, 0, stream>>>(
        values, masks, deltas, Wdx, bdx, bdh, bh, bf, bc,
        b_ih, b_hh, Wo, bo, frags, inv_denom, ws_lossblk, out_imp, out_pred);
    final_kernel<<<1, 256, 0, stream>>>(ws_lossblk, out_loss);
}

// Round 3
// 318.449 us; speedup vs baseline: 1.1393x; 1.1393x over previous
//
#include <hip/hip_runtime.h>
#include <hip/hip_bf16.h>
#include <math.h>

#define BB 4096
#define TT 48
#define FF 64
#define HH 128
#define ROWS 16
#define NT 512
#define NBLK (BB / ROWS)   // 256

typedef __attribute__((ext_vector_type(8))) short short8;
typedef __attribute__((ext_vector_type(4))) float f32x4;

#define MFMA(a, b, c) __builtin_amdgcn_mfma_f32_16x16x32_bf16((a), (b), (c), 0, 0, 0)

__device__ __forceinline__ float sigm(float x) { return 1.f / (1.f + __expf(-x)); }
__device__ __forceinline__ float tanh_f(float x) { return 2.f / (1.f + __expf(-2.f * x)) - 1.f; }

// ---- prep: pre-format ALL weights as bf16 MFMA B-fragments ----
// frag[...][lane][jj]: n = nt*16 + (lane&15), k = ks*32 + (lane>>4)*8 + jj
// Regions (element offsets):
//   [0,131072)        Wcat [512][256]  (W_ih | W_hh), 32 nt x 8 ks
//   [131072,139264)   Wdh  [128][64],   8 nt x 2 ks
//   [139264,147456)   Wh   [64][128],   4 nt x 4 ks
//   [147456,151552)   Wf   [64][64] diag-zeroed, 4 nt x 2 ks
//   [151552,159744)   Wc   [64][128],   4 nt x 4 ks
__global__ __launch_bounds__(256) void prep_kernel(
    const float* __restrict__ W_ih, const float* __restrict__ W_hh,
    const float* __restrict__ Wdh,  const float* __restrict__ Wh,
    const float* __restrict__ Wf,   const float* __restrict__ Wc,
    __hip_bfloat16* __restrict__ frags) {
    const int idx = blockIdx.x * 256 + threadIdx.x;  // < 159744
    float v;
    if (idx < 131072) {
        const int jj = idx & 7;
        const int lane = (idx >> 3) & 63;
        const int ks = (idx >> 9) & 7;
        const int tile = idx >> 12;
        const int n = tile * 16 + (lane & 15);
        const int k = ks * 32 + ((lane >> 4) << 3) + jj;
        v = (k < 128) ? W_ih[n * 128 + k] : W_hh[n * 128 + (k - 128)];
    } else {
        const int u = idx - 131072;
        const int jj = u & 7;
        const int lane = (u >> 3) & 63;
        const int lq = lane & 15, q8 = (lane >> 4) << 3;
        if (u < 8192) {                       // Wdh
            const int ks = (u >> 9) & 1, nt = u >> 10;
            const int n = nt * 16 + lq, k = ks * 32 + q8 + jj;
            v = Wdh[n * 64 + k];
        } else if (u < 16384) {               // Wh
            const int uu = u - 8192;
            const int ks = (uu >> 9) & 3, nt = uu >> 11;
            const int n = nt * 16 + lq, k = ks * 32 + q8 + jj;
            v = Wh[n * 128 + k];
        } else if (u < 20480) {               // Wf (diag zero)
            const int uu = u - 16384;
            const int ks = (uu >> 9) & 1, nt = uu >> 10;
            const int n = nt * 16 + lq, k = ks * 32 + q8 + jj;
            v = (k == n) ? 0.f : Wf[n * 64 + k];
        } else {                              // Wc
            const int uu = u - 20480;
            const int ks = (uu >> 9) & 3, nt = uu >> 11;
            const int n = nt * 16 + lq, k = ks * 32 + q8 + jj;
            v = Wc[n * 128 + k];
        }
    }
    frags[idx] = __float2bfloat16(v);
}

// ---- denom stage 1: partials[t*32+s] = sum over b-slice s (128 rows) of masks[b][t][:]
__global__ __launch_bounds__(256) void denom1_kernel(const float* __restrict__ masks,
                                                     float* __restrict__ partials) {
    const int t = blockIdx.x >> 5;
    const int s = blockIdx.x & 31;
    const int tid = threadIdx.x;
    float acc = 0.f;
    #pragma unroll
    for (int k = 0; k < 8; ++k) {
        const int i = k * 256 + tid;            // 0..2047 float4s
        const int b = s * 128 + (i >> 4);
        const int f = (i & 15) << 2;
        const float4 v = *(const float4*)&masks[((size_t)b * TT + t) * FF + f];
        acc += v.x + v.y + v.z + v.w;
    }
    #pragma unroll
    for (int off = 32; off; off >>= 1) acc += __shfl_down(acc, off, 64);
    __shared__ float red[4];
    if ((tid & 63) == 0) red[tid >> 6] = acc;
    __syncthreads();
    if (tid == 0) partials[blockIdx.x] = red[0] + red[1] + red[2] + red[3];
}

__global__ __launch_bounds__(64) void denom2_kernel(const float* __restrict__ partials,
                                                    float* __restrict__ inv_denom) {
    const int t = threadIdx.x;
    if (t < TT) {
        float s = 0.f;
        #pragma unroll
        for (int i = 0; i < 32; ++i) s += partials[t * 32 + i];
        inv_denom[t] = 1.f / (s + 1e-5f);
    }
}

// ---- Main persistent kernel ----
// Gate B-frags are loop-invariant: W_hh half (128KB) lives in LDS, m/cc parts (64
// VGPR) live in registers. Zero per-step global fragment traffic.
// Phases per step (4 barriers):
//  A: gamma_h + alpha(w0-3) + gates-m (reg frags) + prefetch t+1
//  B: gates-h ks4,5 (LDS frags) ; x_h + x_c (w0-3)
//  C: gates-h ks6,7 (LDS frags) ; z_h + combine + loss + out_imp (w0-3)
//  D: gates-cc (reg frags) + LSTM epilogue + stage t+1
__global__ __launch_bounds__(NT, 2) void rits_kernel(
    const float* __restrict__ values, const float* __restrict__ masks,
    const float* __restrict__ deltas,
    const float* __restrict__ Wdx, const float* __restrict__ bdx,
    const float* __restrict__ bdh, const float* __restrict__ bh,
    const float* __restrict__ bf,  const float* __restrict__ bc,
    const float* __restrict__ b_ih, const float* __restrict__ b_hh,
    const float* __restrict__ Wo,  const float* __restrict__ bo,
    const __hip_bfloat16* __restrict__ frags,
    const float* __restrict__ inv_denom,
    float* __restrict__ ws_lossblk,
    float* __restrict__ out_imp, float* __restrict__ out_pred)
{
    __shared__ short8 whh_frag[8192];            // 128 KB: gates ks4-7 B-frags
    __shared__ __hip_bfloat16 dbuf[ROWS][72];    // deltas (staged in D for t+1)
    __shared__ __hip_bfloat16 gxbuf[ROWS][72];   // gamma_x
    __shared__ __hip_bfloat16 mbuf[ROWS][72];    // m (stored ONCE)
    __shared__ __hip_bfloat16 xcbuf[ROWS][72];   // x_c (B -> C)
    __shared__ __hip_bfloat16 ccbuf[ROWS][72];   // c_c (C -> D)
    __shared__ __hip_bfloat16 hbufB[ROWS][136];  // decayed h (A -> B,C)
    __shared__ float x_lds[ROWS][65];            // x fp32 (D -> B)
    __shared__ float m_lds[ROWS][65];            // m fp32 (D -> B)
    __shared__ float redl[8];

    const int tid = threadIdx.x;
    const int bid = blockIdx.x;
    const int b0 = bid * ROWS;
    const int lane = tid & 63;
    const int wv = tid >> 6;        // wave 0..7
    const int quad = lane >> 4;
    const int lq = lane & 15;
    const int wv3 = wv & 3;

    const float wdx_l = Wdx[lane * (FF + 1)];
    const float bdx_l = bdx[lane];

    const int j_ln = wv * 16 + lq;
    const float bdh_w = bdh[j_ln];                 // gamma tile wv <-> col j_ln
    const float bI = b_ih[j_ln]       + b_hh[j_ln];
    const float bF = b_ih[128 + j_ln] + b_hh[128 + j_ln];
    const float bG = b_ih[256 + j_ln] + b_hh[256 + j_ln];
    const float bO = b_ih[384 + j_ln] + b_hh[384 + j_ln];

    const int f46 = wv3 * 16 + lq;
    const float bh_f = bh[f46];
    const float bf_f = bf[f46];
    const float bc_f = bc[f46];

    const short8* f8 = (const short8*)frags;
    // short8-unit offsets: CAT 0, DH 16384, H 17408, F 18432, C 18944

    // loop-invariant small B-fragments cached in registers
    short8 Bgam[2], Bal[4], Bxh[4], Bzh[2];
    #pragma unroll
    for (int ks = 0; ks < 2; ++ks) Bgam[ks] = f8[16384 + ((wv * 2 + ks) << 6) + lane];
    #pragma unroll
    for (int ks = 0; ks < 4; ++ks) Bal[ks] = f8[18944 + ((wv3 * 4 + ks) << 6) + lane];
    #pragma unroll
    for (int ks = 0; ks < 4; ++ks) Bxh[ks] = f8[17408 + ((wv3 * 4 + ks) << 6) + lane];
    #pragma unroll
    for (int ks = 0; ks < 2; ++ks) Bzh[ks] = f8[18432 + ((wv3 * 2 + ks) << 6) + lane];

    // gate cc-part (ks0,1) and m-part (ks2,3) B-frags: loop-invariant registers
    short8 Bcc[4][2], Bm[4][2];
    #pragma unroll
    for (int g = 0; g < 4; ++g) {
        #pragma unroll
        for (int kk = 0; kk < 2; ++kk) {
            Bcc[g][kk] = f8[(((g * 8 + wv) * 8 + kk)     << 6) + lane];
            Bm[g][kk]  = f8[(((g * 8 + wv) * 8 + 2 + kk) << 6) + lane];
        }
    }
    // gate h-part (ks4-7) B-frags -> LDS (one-time 128KB copy from L2)
    // slot = g*32 + j*4 + kk  <->  f8 frag ((g*8+j)*8 + 4 + kk)
    for (int i = tid; i < 8192; i += NT) {
        const int slot = i >> 6, ln = i & 63;
        const int g = slot >> 5, rem = slot & 31, j = rem >> 2, kk = rem & 3;
        whh_frag[i] = f8[(((g * 8 + j) * 8 + 4 + kk) << 6) + ln];
    }
    const int wbase = (wv << 8) + lane;  // whh_frag idx: + g*2048 + kk*64

    float c_reg[4], h_reg[4];
    #pragma unroll
    for (int r = 0; r < 4; ++r) { c_reg[r] = 0.f; h_reg[r] = 0.f; }
    float loss_acc = 0.f;

    const int base0 = ((b0 + wv) * TT) * FF + lane;
    const int base1 = ((b0 + wv + 8) * TT) * FF + lane;
    const int imp0  = ((b0 + quad * 4) * TT) * FF + f46;

    // ---- prologue: load + stage t=0 ----
    float xn0 = values[base0], mn0 = masks[base0], dn0 = deltas[base0];
    float xn1 = values[base1], mn1 = masks[base1], dn1 = deltas[base1];
    {
        const int r0 = wv, r1 = wv + 8;
        x_lds[r0][lane] = xn0; m_lds[r0][lane] = mn0;
        dbuf[r0][lane]  = __float2bfloat16(dn0);
        gxbuf[r0][lane] = __float2bfloat16(__expf(-fmaxf(fmaf(dn0, wdx_l, bdx_l), 0.f)));
        mbuf[r0][lane]  = __float2bfloat16(mn0);
        x_lds[r1][lane] = xn1; m_lds[r1][lane] = mn1;
        dbuf[r1][lane]  = __float2bfloat16(dn1);
        gxbuf[r1][lane] = __float2bfloat16(__expf(-fmaxf(fmaf(dn1, wdx_l, bdx_l), 0.f)));
        mbuf[r1][lane]  = __float2bfloat16(mn1);
    }
    __syncthreads();

    for (int t = 0; t < TT; ++t) {
        const float invd = inv_denom[t];

        // ---- Phase A: prefetch ; gamma_h ; alpha (w0-3) ; gates-m (reg frags) ----
        {
            const int tn = (t < TT - 1) ? t + 1 : t;
            const int o0 = base0 + tn * FF, o1 = base1 + tn * FF;
            xn0 = values[o0]; mn0 = masks[o0]; dn0 = deltas[o0];
            xn1 = values[o1]; mn1 = masks[o1]; dn1 = deltas[o1];
        }
        f32x4 gacc0 = {0.f,0.f,0.f,0.f}, gacc1 = {0.f,0.f,0.f,0.f};
        f32x4 gacc2 = {0.f,0.f,0.f,0.f}, gacc3 = {0.f,0.f,0.f,0.f};
        #pragma unroll
        for (int kk = 0; kk < 2; ++kk) {
            const short8 a = *(const short8*)&mbuf[lq][kk * 32 + quad * 8];
            gacc0 = MFMA(a, Bm[0][kk], gacc0);
            gacc1 = MFMA(a, Bm[1][kk], gacc1);
            gacc2 = MFMA(a, Bm[2][kk], gacc2);
            gacc3 = MFMA(a, Bm[3][kk], gacc3);
        }
        float al_r[4];
        {
            f32x4 ga = {0.f, 0.f, 0.f, 0.f};
            #pragma unroll
            for (int ks = 0; ks < 2; ++ks) {
                const short8 a = *(const short8*)&dbuf[lq][ks * 32 + quad * 8];
                ga = MFMA(a, Bgam[ks], ga);
            }
            if (wv < 4) {
                f32x4 aa = {0.f, 0.f, 0.f, 0.f};
                #pragma unroll
                for (int ks = 0; ks < 2; ++ks) {
                    const short8 a = *(const short8*)&gxbuf[lq][ks * 32 + quad * 8];
                    aa = MFMA(a, Bal[ks], aa);
                }
                #pragma unroll
                for (int ks = 2; ks < 4; ++ks) {
                    const short8 a = *(const short8*)&mbuf[lq][(ks - 2) * 32 + quad * 8];
                    aa = MFMA(a, Bal[ks], aa);
                }
                #pragma unroll
                for (int r = 0; r < 4; ++r) al_r[r] = aa[r] + bc_f;
            }
            #pragma unroll
            for (int r = 0; r < 4; ++r) {
                const float gh = __expf(-fmaxf(ga[r] + bdh_w, 0.f));
                hbufB[quad * 4 + r][j_ln] = __float2bfloat16(h_reg[r] * gh);
            }
        }
        __syncthreads();

        // ---- Phase B: gates-h ks4,5 (LDS frags) ; x_h + x_c (w0-3) ----
        #pragma unroll
        for (int kk = 0; kk < 2; ++kk) {
            const short8 a = *(const short8*)&hbufB[lq][kk * 32 + quad * 8];
            gacc0 = MFMA(a, whh_frag[wbase + 0    + kk * 64], gacc0);
            gacc1 = MFMA(a, whh_frag[wbase + 2048 + kk * 64], gacc1);
            gacc2 = MFMA(a, whh_frag[wbase + 4096 + kk * 64], gacc2);
            gacc3 = MFMA(a, whh_frag[wbase + 6144 + kk * 64], gacc3);
        }
        float xv_r[4], mv_r[4], xh_r[4];
        float stepsum = 0.f;
        if (wv < 4) {
            f32x4 acc = {0.f, 0.f, 0.f, 0.f};
            #pragma unroll
            for (int ks = 0; ks < 4; ++ks) {
                const short8 a = *(const short8*)&hbufB[lq][ks * 32 + quad * 8];
                acc = MFMA(a, Bxh[ks], acc);
            }
            #pragma unroll
            for (int r = 0; r < 4; ++r) {
                const int row = quad * 4 + r;
                const float xh = acc[r] + bh_f;
                xh_r[r] = xh;
                const float xv = x_lds[row][f46], mv = m_lds[row][f46];
                xv_r[r] = xv; mv_r[r] = mv;
                stepsum += mv * fabsf(xv - xh);
                xcbuf[row][f46] = __float2bfloat16(fmaf(mv, xv, (1.f - mv) * xh));
            }
        }
        __syncthreads();

        // ---- Phase C: gates-h ks6,7 (LDS frags) ; z_h + combine (w0-3) ----
        #pragma unroll
        for (int kk = 2; kk < 4; ++kk) {
            const short8 a = *(const short8*)&hbufB[lq][kk * 32 + quad * 8];
            gacc0 = MFMA(a, whh_frag[wbase + 0    + kk * 64], gacc0);
            gacc1 = MFMA(a, whh_frag[wbase + 2048 + kk * 64], gacc1);
            gacc2 = MFMA(a, whh_frag[wbase + 4096 + kk * 64], gacc2);
            gacc3 = MFMA(a, whh_frag[wbase + 6144 + kk * 64], gacc3);
        }
        if (wv < 4) {
            f32x4 acc5 = {0.f, 0.f, 0.f, 0.f};
            #pragma unroll
            for (int ks = 0; ks < 2; ++ks) {
                const short8 a = *(const short8*)&xcbuf[lq][ks * 32 + quad * 8];
                acc5 = MFMA(a, Bzh[ks], acc5);
            }
            #pragma unroll
            for (int r = 0; r < 4; ++r) {
                const int row = quad * 4 + r;
                const float zh = acc5[r] + bf_f;
                stepsum += mv_r[r] * fabsf(xv_r[r] - zh);
                const float alpha = al_r[r];
                const float ch = fmaf(alpha, zh, (1.f - alpha) * xh_r[r]);
                stepsum += mv_r[r] * fabsf(xv_r[r] - ch);
                const float cc = fmaf(mv_r[r], xv_r[r], (1.f - mv_r[r]) * ch);
                ccbuf[row][f46] = __float2bfloat16(cc);
                out_imp[imp0 + r * (TT * FF) + t * FF] = cc;
            }
        }
        loss_acc = fmaf(stepsum, invd, loss_acc);
        __syncthreads();

        // ---- Phase D: gates-cc (reg frags) ; LSTM epilogue ; stage t+1 ----
        #pragma unroll
        for (int kk = 0; kk < 2; ++kk) {
            const short8 a = *(const short8*)&ccbuf[lq][kk * 32 + quad * 8];
            gacc0 = MFMA(a, Bcc[0][kk], gacc0);
            gacc1 = MFMA(a, Bcc[1][kk], gacc1);
            gacc2 = MFMA(a, Bcc[2][kk], gacc2);
            gacc3 = MFMA(a, Bcc[3][kk], gacc3);
        }
        // stage t+1 (independent of gate results -> overlaps MFMA latency)
        {
            const int r0 = wv, r1 = wv + 8;
            x_lds[r0][lane] = xn0; m_lds[r0][lane] = mn0;
            dbuf[r0][lane]  = __float2bfloat16(dn0);
            gxbuf[r0][lane] = __float2bfloat16(__expf(-fmaxf(fmaf(dn0, wdx_l, bdx_l), 0.f)));
            mbuf[r0][lane]  = __float2bfloat16(mn0);
            x_lds[r1][lane] = xn1; m_lds[r1][lane] = mn1;
            dbuf[r1][lane]  = __float2bfloat16(dn1);
            gxbuf[r1][lane] = __float2bfloat16(__expf(-fmaxf(fmaf(dn1, wdx_l, bdx_l), 0.f)));
            mbuf[r1][lane]  = __float2bfloat16(mn1);
        }
        #pragma unroll
        for (int r = 0; r < 4; ++r) {
            const float ig = sigm(gacc0[r] + bI);
            const float fg = sigm(gacc1[r] + bF);
            const float gg = tanh_f(gacc2[r] + bG);
            const float og = sigm(gacc3[r] + bO);
            c_reg[r] = fmaf(fg, c_reg[r], ig * gg);
            h_reg[r] = og * tanh_f(c_reg[r]);
        }
        __syncthreads();
    }

    // ---- predictions: write final h (regs) to LDS, then reduce h @ Wo.T + bo ----
    #pragma unroll
    for (int r = 0; r < 4; ++r)
        hbufB[quad * 4 + r][j_ln] = __float2bfloat16(h_reg[r]);
    __syncthreads();
    {
        const int r = tid >> 5, l = tid & 31;
        float s = 0.f;
        #pragma unroll
        for (int k = l; k < HH; k += 32) s += __bfloat162float(hbufB[r][k]) * Wo[k];
        #pragma unroll
        for (int off = 16; off; off >>= 1) s += __shfl_down(s, off, 32);
        if (l == 0) out_pred[b0 + r] = s + bo[0];
    }
    // ---- block loss partial ----
    #pragma unroll
    for (int off = 32; off; off >>= 1) loss_acc += __shfl_down(loss_acc, off, 64);
    if (lane == 0) redl[wv] = loss_acc;
    __syncthreads();
    if (tid == 0) {
        float s = 0.f;
        #pragma unroll
        for (int w = 0; w < 8; ++w) s += redl[w];
        ws_lossblk[bid] = s;
    }
}

// ---- final: loss = sum of 256 block partials ----
__global__ __launch_bounds__(256) void final_kernel(const float* __restrict__ ws_lossblk,
                                                    float* __restrict__ out_loss) {
    const int tid = threadIdx.x;
    float s = ws_lossblk[tid];
    #pragma unroll
    for (int off = 32; off; off >>= 1) s += __shfl_down(s, off, 64);
    __shared__ float red[4];
    if ((tid & 63) == 0) red[tid >> 6] = s;
    __syncthreads();
    if (tid == 0) out_loss[0] = red[0] + red[1] + red[2] + red[3];
}

extern "C" void kernel_launch(void* const* d_in, const int* in_sizes, int n_in,
                              void* d_out, int out_size, void* d_ws, size_t ws_size,
                              hipStream_t stream) {
    const float* values = (const float*)d_in[0];
    const float* masks  = (const float*)d_in[1];
    const float* deltas = (const float*)d_in[2];
    const float* Wdh  = (const float*)d_in[3];
    const float* bdh  = (const float*)d_in[4];
    const float* Wdx  = (const float*)d_in[5];
    const float* bdx  = (const float*)d_in[6];
    const float* Wh   = (const float*)d_in[7];
    const float* bh   = (const float*)d_in[8];
    const float* Wf   = (const float*)d_in[9];
    const float* bf   = (const float*)d_in[10];
    const float* Wc   = (const float*)d_in[11];
    const float* bc   = (const float*)d_in[12];
    const float* W_ih = (const float*)d_in[13];
    const float* W_hh = (const float*)d_in[14];
    const float* b_ih = (const float*)d_in[15];
    const float* b_hh = (const float*)d_in[16];
    const float* Wo   = (const float*)d_in[17];
    const float* bo   = (const float*)d_in[18];

    __hip_bfloat16* frags = (__hip_bfloat16*)d_ws;                 // 159744 bf16 = 319488 B
    float* inv_denom  = (float*)((char*)d_ws + 320 * 1024);        // [48] (pad to 64)
    float* partials   = inv_denom + 64;                            // [48*32]
    float* ws_lossblk = partials + 2048;                           // [256]

    float* out_loss = (float*)d_out;
    float* out_imp  = out_loss + 1;
    float* out_pred = out_imp + (size_t)BB * TT * FF;

    prep_kernel<<<624, 256, 0, stream>>>(W_ih, W_hh, Wdh, Wh, Wf, Wc, frags);
    denom1_kernel<<<TT * 32, 256, 0, stream>>>(masks, partials);
    denom2_kernel<<<1, 64, 0, stream>>>(partials, inv_denom);
    rits_kernel<<<NBLK, NT, 0, stream>>>(
        values, masks, deltas, Wdx, bdx, bdh, bh, bf, bc,
        b_ih, b_hh, Wo, bo, frags, inv_denom, ws_lossblk, out_imp, out_pred);
    final_kernel<<<1, 256, 0, stream>>>(ws_lossblk, out_loss);
}

// Round 4
// 317.251 us; speedup vs baseline: 1.1436x; 1.0038x over previous
//
#include <hip/hip_runtime.h>
#include <hip/hip_bf16.h>
#include <math.h>

#define BB 4096
#define TT 48
#define FF 64
#define HH 128
#define ROWS 16
#define NT 512
#define NBLK (BB / ROWS)   // 256

typedef __attribute__((ext_vector_type(8))) short short8;
typedef __attribute__((ext_vector_type(4))) float f32x4;

#define MFMA(a, b, c) __builtin_amdgcn_mfma_f32_16x16x32_bf16((a), (b), (c), 0, 0, 0)

__device__ __forceinline__ float sigm(float x) { return 1.f / (1.f + __expf(-x)); }
__device__ __forceinline__ float tanh_f(float x) { return 2.f / (1.f + __expf(-2.f * x)) - 1.f; }

// ---- prep: pre-format ALL weights as bf16 MFMA B-fragments ----
// frag[...][lane][jj]: n = nt*16 + (lane&15), k = ks*32 + (lane>>4)*8 + jj
// Regions (element offsets):
//   [0,131072)        Wcat [512][256]  (W_ih | W_hh), 32 nt x 8 ks
//   [131072,139264)   Wdh  [128][64],   8 nt x 2 ks
//   [139264,147456)   Wh   [64][128],   4 nt x 4 ks
//   [147456,151552)   Wf   [64][64] diag-zeroed, 4 nt x 2 ks
//   [151552,159744)   Wc   [64][128],   4 nt x 4 ks
__global__ __launch_bounds__(256) void prep_kernel(
    const float* __restrict__ W_ih, const float* __restrict__ W_hh,
    const float* __restrict__ Wdh,  const float* __restrict__ Wh,
    const float* __restrict__ Wf,   const float* __restrict__ Wc,
    __hip_bfloat16* __restrict__ frags) {
    const int idx = blockIdx.x * 256 + threadIdx.x;  // < 159744
    float v;
    if (idx < 131072) {
        const int jj = idx & 7;
        const int lane = (idx >> 3) & 63;
        const int ks = (idx >> 9) & 7;
        const int tile = idx >> 12;
        const int n = tile * 16 + (lane & 15);
        const int k = ks * 32 + ((lane >> 4) << 3) + jj;
        v = (k < 128) ? W_ih[n * 128 + k] : W_hh[n * 128 + (k - 128)];
    } else {
        const int u = idx - 131072;
        const int jj = u & 7;
        const int lane = (u >> 3) & 63;
        const int lq = lane & 15, q8 = (lane >> 4) << 3;
        if (u < 8192) {                       // Wdh
            const int ks = (u >> 9) & 1, nt = u >> 10;
            const int n = nt * 16 + lq, k = ks * 32 + q8 + jj;
            v = Wdh[n * 64 + k];
        } else if (u < 16384) {               // Wh
            const int uu = u - 8192;
            const int ks = (uu >> 9) & 3, nt = uu >> 11;
            const int n = nt * 16 + lq, k = ks * 32 + q8 + jj;
            v = Wh[n * 128 + k];
        } else if (u < 20480) {               // Wf (diag zero)
            const int uu = u - 16384;
            const int ks = (uu >> 9) & 1, nt = uu >> 10;
            const int n = nt * 16 + lq, k = ks * 32 + q8 + jj;
            v = (k == n) ? 0.f : Wf[n * 64 + k];
        } else {                              // Wc
            const int uu = u - 20480;
            const int ks = (uu >> 9) & 3, nt = uu >> 11;
            const int n = nt * 16 + lq, k = ks * 32 + q8 + jj;
            v = Wc[n * 128 + k];
        }
    }
    frags[idx] = __float2bfloat16(v);
}

// ---- denom stage 1: partials[t*32+s] = sum over b-slice s (128 rows) of masks[b][t][:]
__global__ __launch_bounds__(256) void denom1_kernel(const float* __restrict__ masks,
                                                     float* __restrict__ partials) {
    const int t = blockIdx.x >> 5;
    const int s = blockIdx.x & 31;
    const int tid = threadIdx.x;
    float acc = 0.f;
    #pragma unroll
    for (int k = 0; k < 8; ++k) {
        const int i = k * 256 + tid;            // 0..2047 float4s
        const int b = s * 128 + (i >> 4);
        const int f = (i & 15) << 2;
        const float4 v = *(const float4*)&masks[((size_t)b * TT + t) * FF + f];
        acc += v.x + v.y + v.z + v.w;
    }
    #pragma unroll
    for (int off = 32; off; off >>= 1) acc += __shfl_down(acc, off, 64);
    __shared__ float red[4];
    if ((tid & 63) == 0) red[tid >> 6] = acc;
    __syncthreads();
    if (tid == 0) partials[blockIdx.x] = red[0] + red[1] + red[2] + red[3];
}

__global__ __launch_bounds__(64) void denom2_kernel(const float* __restrict__ partials,
                                                    float* __restrict__ inv_denom) {
    const int t = threadIdx.x;
    if (t < TT) {
        float s = 0.f;
        #pragma unroll
        for (int i = 0; i < 32; ++i) s += partials[t * 32 + i];
        inv_denom[t] = 1.f / (s + 1e-5f);
    }
}

// ---- Main persistent kernel ----
// Gate B-frags are loop-invariant: W_hh half (128KB) lives in LDS, m/cc parts live in
// registers. amdgpu_waves_per_eu(2,2) pins the allocator's occupancy target to the TRUE
// runtime occupancy (1 block x 8 waves/CU = 2 waves/EU): without it the backend targets
// 4 waves/EU (VGPR<=128 -> got 120), which cannot hold the ~112 VGPRs of declared
// fragment registers, so it rematerialized them as per-step global loads (~128KB/step/CU
// from L2) -- the same pathology round 3 fixed for whh.
// Phases per step (4 barriers):
//  A: gamma_h + alpha(w0-3) + gates-m (reg frags) + prefetch t+1
//  B: gates-h ks4,5 (LDS frags) ; x_h + x_c (w0-3)
//  C: gates-h ks6,7 (LDS frags) ; z_h + combine + loss + out_imp (w0-3)
//  D: gates-cc (reg frags) + LSTM epilogue + stage t+1
__global__ __launch_bounds__(NT)
__attribute__((amdgpu_waves_per_eu(2, 2)))
void rits_kernel(
    const float* __restrict__ values, const float* __restrict__ masks,
    const float* __restrict__ deltas,
    const float* __restrict__ Wdx, const float* __restrict__ bdx,
    const float* __restrict__ bdh, const float* __restrict__ bh,
    const float* __restrict__ bf,  const float* __restrict__ bc,
    const float* __restrict__ b_ih, const float* __restrict__ b_hh,
    const float* __restrict__ Wo,  const float* __restrict__ bo,
    const __hip_bfloat16* __restrict__ frags,
    const float* __restrict__ inv_denom,
    float* __restrict__ ws_lossblk,
    float* __restrict__ out_imp, float* __restrict__ out_pred)
{
    __shared__ short8 whh_frag[8192];            // 128 KB: gates ks4-7 B-frags
    __shared__ __hip_bfloat16 dbuf[ROWS][72];    // deltas (staged in D for t+1)
    __shared__ __hip_bfloat16 gxbuf[ROWS][72];   // gamma_x
    __shared__ __hip_bfloat16 mbuf[ROWS][72];    // m (stored ONCE)
    __shared__ __hip_bfloat16 xcbuf[ROWS][72];   // x_c (B -> C)
    __shared__ __hip_bfloat16 ccbuf[ROWS][72];   // c_c (C -> D)
    __shared__ __hip_bfloat16 hbufB[ROWS][136];  // decayed h (A -> B,C)
    __shared__ float x_lds[ROWS][65];            // x fp32 (D -> B)
    __shared__ float m_lds[ROWS][65];            // m fp32 (D -> B)
    __shared__ float redl[8];

    const int tid = threadIdx.x;
    const int bid = blockIdx.x;
    const int b0 = bid * ROWS;
    const int lane = tid & 63;
    const int wv = tid >> 6;        // wave 0..7
    const int quad = lane >> 4;
    const int lq = lane & 15;
    const int wv3 = wv & 3;

    const float wdx_l = Wdx[lane * (FF + 1)];
    const float bdx_l = bdx[lane];

    const int j_ln = wv * 16 + lq;
    const float bdh_w = bdh[j_ln];                 // gamma tile wv <-> col j_ln
    const float bI = b_ih[j_ln]       + b_hh[j_ln];
    const float bF = b_ih[128 + j_ln] + b_hh[128 + j_ln];
    const float bG = b_ih[256 + j_ln] + b_hh[256 + j_ln];
    const float bO = b_ih[384 + j_ln] + b_hh[384 + j_ln];

    const int f46 = wv3 * 16 + lq;
    const float bh_f = bh[f46];
    const float bf_f = bf[f46];
    const float bc_f = bc[f46];

    const short8* f8 = (const short8*)frags;
    // short8-unit offsets: CAT 0, DH 16384, H 17408, F 18432, C 18944

    // loop-invariant small B-fragments cached in registers
    short8 Bgam[2], Bal[4], Bxh[4], Bzh[2];
    #pragma unroll
    for (int ks = 0; ks < 2; ++ks) Bgam[ks] = f8[16384 + ((wv * 2 + ks) << 6) + lane];
    #pragma unroll
    for (int ks = 0; ks < 4; ++ks) Bal[ks] = f8[18944 + ((wv3 * 4 + ks) << 6) + lane];
    #pragma unroll
    for (int ks = 0; ks < 4; ++ks) Bxh[ks] = f8[17408 + ((wv3 * 4 + ks) << 6) + lane];
    #pragma unroll
    for (int ks = 0; ks < 2; ++ks) Bzh[ks] = f8[18432 + ((wv3 * 2 + ks) << 6) + lane];

    // gate cc-part (ks0,1) and m-part (ks2,3) B-frags: loop-invariant registers
    short8 Bcc[4][2], Bm[4][2];
    #pragma unroll
    for (int g = 0; g < 4; ++g) {
        #pragma unroll
        for (int kk = 0; kk < 2; ++kk) {
            Bcc[g][kk] = f8[(((g * 8 + wv) * 8 + kk)     << 6) + lane];
            Bm[g][kk]  = f8[(((g * 8 + wv) * 8 + 2 + kk) << 6) + lane];
        }
    }
    // gate h-part (ks4-7) B-frags -> LDS (one-time 128KB copy from L2)
    // slot = g*32 + j*4 + kk  <->  f8 frag ((g*8+j)*8 + 4 + kk)
    for (int i = tid; i < 8192; i += NT) {
        const int slot = i >> 6, ln = i & 63;
        const int g = slot >> 5, rem = slot & 31, j = rem >> 2, kk = rem & 3;
        whh_frag[i] = f8[(((g * 8 + j) * 8 + 4 + kk) << 6) + ln];
    }
    const int wbase = (wv << 8) + lane;  // whh_frag idx: + g*2048 + kk*64

    float c_reg[4], h_reg[4];
    #pragma unroll
    for (int r = 0; r < 4; ++r) { c_reg[r] = 0.f; h_reg[r] = 0.f; }
    float loss_acc = 0.f;

    const int base0 = ((b0 + wv) * TT) * FF + lane;
    const int base1 = ((b0 + wv + 8) * TT) * FF + lane;
    const int imp0  = ((b0 + quad * 4) * TT) * FF + f46;

    // ---- prologue: load + stage t=0 ----
    float xn0 = values[base0], mn0 = masks[base0], dn0 = deltas[base0];
    float xn1 = values[base1], mn1 = masks[base1], dn1 = deltas[base1];
    {
        const int r0 = wv, r1 = wv + 8;
        x_lds[r0][lane] = xn0; m_lds[r0][lane] = mn0;
        dbuf[r0][lane]  = __float2bfloat16(dn0);
        gxbuf[r0][lane] = __float2bfloat16(__expf(-fmaxf(fmaf(dn0, wdx_l, bdx_l), 0.f)));
        mbuf[r0][lane]  = __float2bfloat16(mn0);
        x_lds[r1][lane] = xn1; m_lds[r1][lane] = mn1;
        dbuf[r1][lane]  = __float2bfloat16(dn1);
        gxbuf[r1][lane] = __float2bfloat16(__expf(-fmaxf(fmaf(dn1, wdx_l, bdx_l), 0.f)));
        mbuf[r1][lane]  = __float2bfloat16(mn1);
    }
    __syncthreads();

    for (int t = 0; t < TT; ++t) {
        const float invd = inv_denom[t];

        // ---- Phase A: prefetch ; gamma_h ; alpha (w0-3) ; gates-m (reg frags) ----
        {
            const int tn = (t < TT - 1) ? t + 1 : t;
            const int o0 = base0 + tn * FF, o1 = base1 + tn * FF;
            xn0 = values[o0]; mn0 = masks[o0]; dn0 = deltas[o0];
            xn1 = values[o1]; mn1 = masks[o1]; dn1 = deltas[o1];
        }
        f32x4 gacc0 = {0.f,0.f,0.f,0.f}, gacc1 = {0.f,0.f,0.f,0.f};
        f32x4 gacc2 = {0.f,0.f,0.f,0.f}, gacc3 = {0.f,0.f,0.f,0.f};
        #pragma unroll
        for (int kk = 0; kk < 2; ++kk) {
            const short8 a = *(const short8*)&mbuf[lq][kk * 32 + quad * 8];
            gacc0 = MFMA(a, Bm[0][kk], gacc0);
            gacc1 = MFMA(a, Bm[1][kk], gacc1);
            gacc2 = MFMA(a, Bm[2][kk], gacc2);
            gacc3 = MFMA(a, Bm[3][kk], gacc3);
        }
        float al_r[4];
        {
            f32x4 ga = {0.f, 0.f, 0.f, 0.f};
            #pragma unroll
            for (int ks = 0; ks < 2; ++ks) {
                const short8 a = *(const short8*)&dbuf[lq][ks * 32 + quad * 8];
                ga = MFMA(a, Bgam[ks], ga);
            }
            if (wv < 4) {
                f32x4 aa = {0.f, 0.f, 0.f, 0.f};
                #pragma unroll
                for (int ks = 0; ks < 2; ++ks) {
                    const short8 a = *(const short8*)&gxbuf[lq][ks * 32 + quad * 8];
                    aa = MFMA(a, Bal[ks], aa);
                }
                #pragma unroll
                for (int ks = 2; ks < 4; ++ks) {
                    const short8 a = *(const short8*)&mbuf[lq][(ks - 2) * 32 + quad * 8];
                    aa = MFMA(a, Bal[ks], aa);
                }
                #pragma unroll
                for (int r = 0; r < 4; ++r) al_r[r] = aa[r] + bc_f;
            }
            #pragma unroll
            for (int r = 0; r < 4; ++r) {
                const float gh = __expf(-fmaxf(ga[r] + bdh_w, 0.f));
                hbufB[quad * 4 + r][j_ln] = __float2bfloat16(h_reg[r] * gh);
            }
        }
        __syncthreads();

        // ---- Phase B: gates-h ks4,5 (LDS frags) ; x_h + x_c (w0-3) ----
        #pragma unroll
        for (int kk = 0; kk < 2; ++kk) {
            const short8 a = *(const short8*)&hbufB[lq][kk * 32 + quad * 8];
            gacc0 = MFMA(a, whh_frag[wbase + 0    + kk * 64], gacc0);
            gacc1 = MFMA(a, whh_frag[wbase + 2048 + kk * 64], gacc1);
            gacc2 = MFMA(a, whh_frag[wbase + 4096 + kk * 64], gacc2);
            gacc3 = MFMA(a, whh_frag[wbase + 6144 + kk * 64], gacc3);
        }
        float xv_r[4], mv_r[4], xh_r[4];
        float stepsum = 0.f;
        if (wv < 4) {
            f32x4 acc = {0.f, 0.f, 0.f, 0.f};
            #pragma unroll
            for (int ks = 0; ks < 4; ++ks) {
                const short8 a = *(const short8*)&hbufB[lq][ks * 32 + quad * 8];
                acc = MFMA(a, Bxh[ks], acc);
            }
            #pragma unroll
            for (int r = 0; r < 4; ++r) {
                const int row = quad * 4 + r;
                const float xh = acc[r] + bh_f;
                xh_r[r] = xh;
                const float xv = x_lds[row][f46], mv = m_lds[row][f46];
                xv_r[r] = xv; mv_r[r] = mv;
                stepsum += mv * fabsf(xv - xh);
                xcbuf[row][f46] = __float2bfloat16(fmaf(mv, xv, (1.f - mv) * xh));
            }
        }
        __syncthreads();

        // ---- Phase C: gates-h ks6,7 (LDS frags) ; z_h + combine (w0-3) ----
        #pragma unroll
        for (int kk = 2; kk < 4; ++kk) {
            const short8 a = *(const short8*)&hbufB[lq][kk * 32 + quad * 8];
            gacc0 = MFMA(a, whh_frag[wbase + 0    + kk * 64], gacc0);
            gacc1 = MFMA(a, whh_frag[wbase + 2048 + kk * 64], gacc1);
            gacc2 = MFMA(a, whh_frag[wbase + 4096 + kk * 64], gacc2);
            gacc3 = MFMA(a, whh_frag[wbase + 6144 + kk * 64], gacc3);
        }
        if (wv < 4) {
            f32x4 acc5 = {0.f, 0.f, 0.f, 0.f};
            #pragma unroll
            for (int ks = 0; ks < 2; ++ks) {
                const short8 a = *(const short8*)&xcbuf[lq][ks * 32 + quad * 8];
                acc5 = MFMA(a, Bzh[ks], acc5);
            }
            #pragma unroll
            for (int r = 0; r < 4; ++r) {
                const int row = quad * 4 + r;
                const float zh = acc5[r] + bf_f;
                stepsum += mv_r[r] * fabsf(xv_r[r] - zh);
                const float alpha = al_r[r];
                const float ch = fmaf(alpha, zh, (1.f - alpha) * xh_r[r]);
                stepsum += mv_r[r] * fabsf(xv_r[r] - ch);
                const float cc = fmaf(mv_r[r], xv_r[r], (1.f - mv_r[r]) * ch);
                ccbuf[row][f46] = __float2bfloat16(cc);
                out_imp[imp0 + r * (TT * FF) + t * FF] = cc;
            }
        }
        loss_acc = fmaf(stepsum, invd, loss_acc);
        __syncthreads();

        // ---- Phase D: gates-cc (reg frags) ; LSTM epilogue ; stage t+1 ----
        #pragma unroll
        for (int kk = 0; kk < 2; ++kk) {
            const short8 a = *(const short8*)&ccbuf[lq][kk * 32 + quad * 8];
            gacc0 = MFMA(a, Bcc[0][kk], gacc0);
            gacc1 = MFMA(a, Bcc[1][kk], gacc1);
            gacc2 = MFMA(a, Bcc[2][kk], gacc2);
            gacc3 = MFMA(a, Bcc[3][kk], gacc3);
        }
        // stage t+1 (independent of gate results -> overlaps MFMA latency)
        {
            const int r0 = wv, r1 = wv + 8;
            x_lds[r0][lane] = xn0; m_lds[r0][lane] = mn0;
            dbuf[r0][lane]  = __float2bfloat16(dn0);
            gxbuf[r0][lane] = __float2bfloat16(__expf(-fmaxf(fmaf(dn0, wdx_l, bdx_l), 0.f)));
            mbuf[r0][lane]  = __float2bfloat16(mn0);
            x_lds[r1][lane] = xn1; m_lds[r1][lane] = mn1;
            dbuf[r1][lane]  = __float2bfloat16(dn1);
            gxbuf[r1][lane] = __float2bfloat16(__expf(-fmaxf(fmaf(dn1, wdx_l, bdx_l), 0.f)));
            mbuf[r1][lane]  = __float2bfloat16(mn1);
        }
        #pragma unroll
        for (int r = 0; r < 4; ++r) {
            const float ig = sigm(gacc0[r] + bI);
            const float fg = sigm(gacc1[r] + bF);
            const float gg = tanh_f(gacc2[r] + bG);
            const float og = sigm(gacc3[r] + bO);
            c_reg[r] = fmaf(fg, c_reg[r], ig * gg);
            h_reg[r] = og * tanh_f(c_reg[r]);
        }
        __syncthreads();
    }

    // ---- predictions: write final h (regs) to LDS, then reduce h @ Wo.T + bo ----
    #pragma unroll
    for (int r = 0; r < 4; ++r)
        hbufB[quad * 4 + r][j_ln] = __float2bfloat16(h_reg[r]);
    __syncthreads();
    {
        const int r = tid >> 5, l = tid & 31;
        float s = 0.f;
        #pragma unroll
        for (int k = l; k < HH; k += 32) s += __bfloat162float(hbufB[r][k]) * Wo[k];
        #pragma unroll
        for (int off = 16; off; off >>= 1) s += __shfl_down(s, off, 32);
        if (l == 0) out_pred[b0 + r] = s + bo[0];
    }
    // ---- block loss partial ----
    #pragma unroll
    for (int off = 32; off; off >>= 1) loss_acc += __shfl_down(loss_acc, off, 64);
    if (lane == 0) redl[wv] = loss_acc;
    __syncthreads();
    if (tid == 0) {
        float s = 0.f;
        #pragma unroll
        for (int w = 0; w < 8; ++w) s += redl[w];
        ws_lossblk[bid] = s;
    }
}

// ---- final: loss = sum of 256 block partials ----
__global__ __launch_bounds__(256) void final_kernel(const float* __restrict__ ws_lossblk,
                                                    float* __restrict__ out_loss) {
    const int tid = threadIdx.x;
    float s = ws_lossblk[tid];
    #pragma unroll
    for (int off = 32; off; off >>= 1) s += __shfl_down(s, off, 64);
    __shared__ float red[4];
    if ((tid & 63) == 0) red[tid >> 6] = s;
    __syncthreads();
    if (tid == 0) out_loss[0] = red[0] + red[1] + red[2] + red[3];
}

extern "C" void kernel_launch(void* const* d_in, const int* in_sizes, int n_in,
                              void* d_out, int out_size, void* d_ws, size_t ws_size,
                              hipStream_t stream) {
    const float* values = (const float*)d_in[0];
    const float* masks  = (const float*)d_in[1];
    const float* deltas = (const float*)d_in[2];
    const float* Wdh  = (const float*)d_in[3];
    const float* bdh  = (const float*)d_in[4];
    const float* Wdx  = (const float*)d_in[5];
    const float* bdx  = (const float*)d_in[6];
    const float* Wh   = (const float*)d_in[7];
    const float* bh   = (const float*)d_in[8];
    const float* Wf   = (const float*)d_in[9];
    const float* bf   = (const float*)d_in[10];
    const float* Wc   = (const float*)d_in[11];
    const float* bc   = (const float*)d_in[12];
    const float* W_ih = (const float*)d_in[13];
    const float* W_hh = (const float*)d_in[14];
    const float* b_ih = (const float*)d_in[15];
    const float* b_hh = (const float*)d_in[16];
    const float* Wo   = (const float*)d_in[17];
    const float* bo   = (const float*)d_in[18];

    __hip_bfloat16* frags = (__hip_bfloat16*)d_ws;                 // 159744 bf16 = 319488 B
    float* inv_denom  = (float*)((char*)d_ws + 320 * 1024);        // [48] (pad to 64)
    float* partials   = inv_denom + 64;                            // [48*32]
    float* ws_lossblk = partials + 2048;                           // [256]

    float* out_loss = (float*)d_out;
    float* out_imp  = out_loss + 1;
    float* out_pred = out_imp + (size_t)BB * TT * FF;

    prep_kernel<<<624, 256, 0, stream>>>(W_ih, W_hh, Wdh, Wh, Wf, Wc, frags);
    denom1_kernel<<<TT * 32, 256, 0, stream>>>(masks, partials);
    denom2_kernel<<<1, 64, 0, stream>>>(partials, inv_denom);
    rits_kernel<<<NBLK, NT, 0, stream>>>(
        values, masks, deltas, Wdx, bdx, bdh, bh, bf, bc,
        b_ih, b_hh, Wo, bo, frags, inv_denom, ws_lossblk, out_imp, out_pred);
    final_kernel<<<1, 256, 0, stream>>>(ws_lossblk, out_loss);
}